// Round 6
// baseline (208.115 us; speedup 1.0000x reference)
//
#include <hip/hip_runtime.h>

typedef unsigned short u16;
typedef __attribute__((ext_vector_type(8))) short short8;
typedef __attribute__((ext_vector_type(4))) float f32x4;

// ---------- helpers ----------
__device__ inline u16 f2bf(float f) {
    union { float f; unsigned u; } v; v.f = f;
    unsigned u = v.u;
    unsigned r = (u + 0x7FFFu + ((u >> 16) & 1u)) >> 16;
    return (u16)r;
}
__device__ inline float bf2f(u16 h) {
    union { unsigned u; float f; } v; v.u = ((unsigned)h) << 16;
    return v.f;
}
// fast rcp/sqrt (~2^-21 rel err; tolerance is bf16-level 0.0078 -> free).
__device__ inline float frcp(float x) { return __builtin_amdgcn_rcpf(x); }
__device__ inline float fsqrt(float x) { return __builtin_amdgcn_sqrtf(x); }
__device__ inline float ftanh(float x) {
    float e = __expf(2.f * x);
    return 1.f - 2.f * frcp(e + 1.f);
}
__device__ inline float4 bf4f(ushort4 u) {
    float4 f; f.x = bf2f(u.x); f.y = bf2f(u.y); f.z = bf2f(u.z); f.w = bf2f(u.w);
    return f;
}

// 16B async global->LDS. Pass a WAVE-UNIFORM LDS base; HW adds lane*16.
// Global src addr is per-lane. Zero VGPR staging cost.
typedef const __attribute__((address_space(1))) void* gas_ptr;
typedef __attribute__((address_space(3))) void* las_ptr;
__device__ __forceinline__ void gl2lds16(const u16* g, u16* l) {
    __builtin_amdgcn_global_load_lds((gas_ptr)(const void*)g, (las_ptr)(void*)l, 16, 0, 0);
}

// ---------- kernel 1: mask + bf16 cast + row norms; tail blocks do W transpose ----------
__global__ __launch_bounds__(128) void prep_kernel(
    const float* __restrict__ F0r, const float* __restrict__ F1r,
    const float* __restrict__ m0, const float* __restrict__ m1,
    const float* __restrict__ W0, const float* __restrict__ W1,
    u16* __restrict__ F0b, u16* __restrict__ F1b,
    u16* __restrict__ WT0, u16* __restrict__ WT1,
    float* __restrict__ sq0, float* __restrict__ sq1)
{
    int bx = blockIdx.x;
    int t = threadIdx.x;
    if (bx >= 16384) {
        // W [256 s][512 d] fp32 -> WT [512 d][256 s] bf16, via [32 s][64 d] LDS tiles.
        __shared__ u16 Wl[64][40];
        int idx2 = bx - 16384;
        int a = idx2 >> 6;
        int tile = idx2 & 63;
        int s0 = (tile >> 3) * 32, d0 = (tile & 7) * 64;
        const float* W = a ? W1 : W0;
        u16* WT = a ? WT1 : WT0;
        #pragma unroll
        for (int i = 0; i < 4; ++i) {
            int idx = i * 512 + t * 4;
            int sl = idx >> 6, dl = idx & 63;
            float4 v = *(const float4*)(W + (size_t)(s0 + sl) * 512 + d0 + dl);
            Wl[dl + 0][sl] = f2bf(v.x);
            Wl[dl + 1][sl] = f2bf(v.y);
            Wl[dl + 2][sl] = f2bf(v.z);
            Wl[dl + 3][sl] = f2bf(v.w);
        }
        __syncthreads();
        #pragma unroll
        for (int i = 0; i < 4; ++i) {
            int idx = i * 512 + t * 4;
            int dl = idx >> 5, sl = idx & 31;
            ushort4 v;
            v.x = Wl[dl][sl + 0]; v.y = Wl[dl][sl + 1];
            v.z = Wl[dl][sl + 2]; v.w = Wl[dl][sl + 3];
            *(ushort4*)(WT + (size_t)(d0 + dl) * 256 + s0 + sl) = v;
        }
        return;
    }
    int bs = bx;                  // b*256 + s
    size_t base = (size_t)bs * 512 + t * 4;
    float mk0 = m0[bs], mk1 = m1[bs];
    float4 v0 = *(const float4*)(F0r + base);
    float4 v1 = *(const float4*)(F1r + base);
    v0.x *= mk0; v0.y *= mk0; v0.z *= mk0; v0.w *= mk0;
    v1.x *= mk1; v1.y *= mk1; v1.z *= mk1; v1.w *= mk1;
    ushort4 u0; u0.x = f2bf(v0.x); u0.y = f2bf(v0.y); u0.z = f2bf(v0.z); u0.w = f2bf(v0.w);
    ushort4 u1; u1.x = f2bf(v1.x); u1.y = f2bf(v1.y); u1.z = f2bf(v1.z); u1.w = f2bf(v1.w);
    *(ushort4*)(F0b + base) = u0;
    *(ushort4*)(F1b + base) = u1;
    float s0p = v0.x*v0.x + v0.y*v0.y + v0.z*v0.z + v0.w*v0.w;
    float s1p = v1.x*v1.x + v1.y*v1.y + v1.z*v1.z + v1.w*v1.w;
    #pragma unroll
    for (int off = 32; off > 0; off >>= 1) {
        s0p += __shfl_xor(s0p, off);
        s1p += __shfl_xor(s1p, off);
    }
    __shared__ float red0[2], red1[2];
    if ((t & 63) == 0) { red0[t >> 6] = s0p; red1[t >> 6] = s1p; }
    __syncthreads();
    if (t == 0) { sq0[bs] = red0[0] + red0[1]; sq1[bs] = red1[0] + red1[1]; }
}

// ---------- kernel 2: FUSED cross-GEMM strip + Fa-GEMM + conv + tanh + avgpool ----------
// Rationale (rounds 0-5): three serialized latency-bound launches left a
// constant 134 us outside fa_conv; A's HBM round-trip and the gemm launch are
// removable by recomputing the 36x256 A-strip each block needs (12.6 MFLOP --
// matrix pipe is 9% busy). Phase 1 = gemm_cross's verified MFMA core
// (M=48/N=256/K=512, gl2lds + XOR swizzle) writing A-strip into Al[36][264];
// phase 2 = round-5 fa_conv verbatim.
// side=1: strip rows i of A (S=F0 strip, G=F1 full);  out1 from F1.
// side=0: strip rows j of A^T (S=F1 strip, G=F0 full); out0 from F0.
// LDS: Al 19.0 KB + 42.3 KB union region (ph1: Gl[256][64] | Sl[48][64];
// ph2: BlBuf 2x[128][64] | Fl[36][132]) = 61.3 KB -> 2 blocks/CU.
__global__ __launch_bounds__(256) void fused_kernel(
    const u16* __restrict__ F0b, const u16* __restrict__ F1b,
    const float* __restrict__ sq0, const float* __restrict__ sq1,
    const u16* __restrict__ WT0, const u16* __restrict__ WT1,
    const u16* __restrict__ F0b2, const u16* __restrict__ F1b2,
    const float* __restrict__ cw, const float* __restrict__ cb,
    float* __restrict__ out)
{
    __shared__ __align__(16) u16 Al[36][264];     // A-strip, phase-2 A operand, 19.0 KB
    __shared__ __align__(16) u16 region[21136];   // 42.3 KB union (see header comment)
    u16 (*Fl)[132] = (u16(*)[132])(region + 16384);

    int b = blockIdx.y, side = blockIdx.z;
    int s0 = blockIdx.x * 32;
    const u16* Sp  = (side ? F0b : F1b) + (size_t)b * 131072;  // strip operand
    const u16* Gp  = (side ? F1b : F0b) + (size_t)b * 131072;  // full-K operand
    const float* sqS = (side ? sq0 : sq1) + b * 256;
    const float* sqG = (side ? sq1 : sq0) + b * 256;
    const u16* WT = side ? WT1 : WT0;
    const u16* Fb = (side ? F1b : F0b) + (size_t)b * 131072;   // conv F source
    float* o = out + (size_t)side * 8388608 + (size_t)b * 131072;

    const int t = threadIdx.x;
    const int lane = t & 63, w = t >> 6;
    const int q = lane >> 4, lm = lane & 15;

    // ===== phase 1: P[m][j] = S[m,:].G[j,:] for m=0..47 (36 used), j=0..255 =====
    f32x4 acc1[3][4];
    #pragma unroll
    for (int x = 0; x < 3; ++x)
        #pragma unroll
        for (int cn = 0; cn < 4; ++cn)
            acc1[x][cn] = (f32x4){0.f, 0.f, 0.f, 0.f};

    for (int kc = 0; kc < 512; kc += 64) {
        __syncthreads();                 // prior chunk's MFMA reads done
        // stage G chunk: 256 rows x 64 k, inverse-swizzled source
        #pragma unroll
        for (int i = 0; i < 8; ++i) {
            int idx = i * 256 + t;
            int r = idx >> 3, seg = idx & 7;
            int ss = seg ^ (r & 7);
            gl2lds16(Gp + (size_t)r * 512 + kc + ss * 8,
                     &region[(i * 256 + w * 64) * 8]);
        }
        // stage S chunk: 48 rows x 64 k (rows clamped; OOB zeroed in epilogue)
        {
            int idx = t;
            int r = idx >> 3, seg = idx & 7;
            int ss = seg ^ (r & 7);
            int s = s0 - 2 + r; s = s < 0 ? 0 : (s > 255 ? 255 : s);
            gl2lds16(Sp + (size_t)s * 512 + kc + ss * 8,
                     &region[16384 + (w * 64) * 8]);
        }
        if (t < 128) {
            int idx = 256 + t;
            int r = idx >> 3, seg = idx & 7;
            int ss = seg ^ (r & 7);
            int s = s0 - 2 + r; s = s < 0 ? 0 : (s > 255 ? 255 : s);
            gl2lds16(Sp + (size_t)s * 512 + kc + ss * 8,
                     &region[16384 + (256 + w * 64) * 8]);
        }
        __syncthreads();                 // chunk staged
        #pragma unroll
        for (int ks = 0; ks < 64; ks += 32) {
            int su = (((ks >> 3) + q) ^ (lm & 7)) * 8;   // read-side swizzle
            short8 af[3], bfr[4];
            #pragma unroll
            for (int x = 0; x < 3; ++x)
                af[x] = *(const short8*)&region[16384 + (x * 16 + lm) * 64 + su];
            #pragma unroll
            for (int cn = 0; cn < 4; ++cn)
                bfr[cn] = *(const short8*)&region[(w * 64 + cn * 16 + lm) * 64 + su];
            #pragma unroll
            for (int x = 0; x < 3; ++x)
                #pragma unroll
                for (int cn = 0; cn < 4; ++cn)
                    acc1[x][cn] = __builtin_amdgcn_mfma_f32_16x16x32_bf16(
                        af[x], bfr[cn], acc1[x][cn], 0, 0, 0);
        }
    }
    __syncthreads();                     // all phase-1 region reads done

    // epilogue: d2 -> A, write strip into Al (C-layout: row=x*16+q*4+r, col=w*64+cn*16+lm)
    float sqg[4];
    #pragma unroll
    for (int cn = 0; cn < 4; ++cn) sqg[cn] = sqG[w * 64 + cn * 16 + lm];
    #pragma unroll
    for (int x = 0; x < 3; ++x) {
        #pragma unroll
        for (int r = 0; r < 4; ++r) {
            int m = x * 16 + q * 4 + r;
            if (m < 36) {
                int s = s0 - 2 + m;
                bool ok = (unsigned)s < 256u;
                float sqs = ok ? sqS[s] : 0.f;
                #pragma unroll
                for (int cn = 0; cn < 4; ++cn) {
                    float d2 = fmaxf(sqs + sqg[cn] - 2.f * acc1[x][cn][r], 0.f);
                    float a = ok ? frcp(1.f + fsqrt(d2)) : 0.f;
                    Al[m][w * 64 + cn * 16 + lm] = f2bf(a);
                }
            }
        }
    }
    // NOTE: no barrier needed before STAGE_B -- epilogue doesn't touch region,
    // and the n0-loop's kb_i=0 barrier makes Al visible + drains the stage.

    // ===== phase 2: Fa-GEMM + conv (round-5 fa_conv, Al computed in-kernel) =====
#define STAGE_B(bufo, nn, kb) do {                                             \
    _Pragma("unroll")                                                          \
    for (int i_ = 0; i_ < 4; ++i_) {                                           \
        int idx_ = i_ * 256 + t;                                               \
        int r_ = idx_ >> 3, seg_ = idx_ & 7;                                   \
        int ss_ = seg_ ^ (r_ & 7);                                             \
        gl2lds16(WT + (size_t)((nn) + r_) * 256 + (kb) + ss_ * 8,              \
                 &region[(bufo) + (i_ * 256 + w * 64) * 8]);                   \
    } } while (0)

    // A-fragment row pointers; x=2 rows >=36 dead (outputs discarded) -> clamp
    const u16* aRow[3];
    aRow[0] = &Al[lm][0];
    aRow[1] = &Al[16 + lm][0];
    aRow[2] = &Al[(lm < 4) ? (32 + lm) : 0][0];

    float w00 = cw[0], w01 = cw[1], w02 = cw[2];
    float w10 = cw[3], w11 = cw[4], w12 = cw[5];
    float bias = cb[0];
    const float third = 1.f / 3.f;
    const int g = t >> 5;               // 0..7: out-row group (4 rows)
    const int dl = (t & 31) * 4;        // d within chunk

    STAGE_B(0, 0, 0);                   // prologue: n0=0, kb=0 -> buf0

    for (int n0 = 0; n0 < 512; n0 += 128) {
        f32x4 acc[3][2];
        #pragma unroll
        for (int x = 0; x < 3; ++x)
            #pragma unroll
            for (int y = 0; y < 2; ++y)
                acc[x][y] = (f32x4){0.f, 0.f, 0.f, 0.f};

        #pragma unroll
        for (int kb_i = 0; kb_i < 4; ++kb_i) {
            __syncthreads();            // drains stage kb_i (hidden under prior phase)
            if (kb_i < 3)
                STAGE_B(((kb_i + 1) & 1) * 8192, n0, (kb_i + 1) * 64);
            const int cbuf = (kb_i & 1) * 8192;
            const int kb = kb_i * 64;
            #pragma unroll
            for (int ks = 0; ks < 64; ks += 32) {
                short8 af[3], bfr[2];
                #pragma unroll
                for (int x = 0; x < 3; ++x)
                    af[x] = *(const short8*)(aRow[x] + kb + ks + q * 8);
                #pragma unroll
                for (int y = 0; y < 2; ++y) {
                    int rb = w * 32 + y * 16 + lm;
                    int su = (((ks >> 3) + q) ^ (lm & 7)) * 8;
                    bfr[y] = *(const short8*)&region[cbuf + rb * 64 + su];
                }
                #pragma unroll
                for (int x = 0; x < 3; ++x)
                    #pragma unroll
                    for (int y = 0; y < 2; ++y)
                        acc[x][y] = __builtin_amdgcn_mfma_f32_16x16x32_bf16(
                            af[x], bfr[y], acc[x][y], 0, 0, 0);
            }
        }

        // issue conv F-loads: latency overlaps Fl-write phase, drained at barrier
        ushort4 frg[8];
        #pragma unroll
        for (int k = 0; k < 8; ++k) {
            int s = s0 + g * 4 - 2 + k;
            ushort4 z = {0, 0, 0, 0};
            frg[k] = ((unsigned)s < 256u)
                   ? *(const ushort4*)(Fb + (size_t)s * 512 + n0 + dl) : z;
        }

        // stage Fa (bf16) into Fl
        #pragma unroll
        for (int x = 0; x < 3; ++x)
            #pragma unroll
            for (int r = 0; r < 4; ++r) {
                int m = x * 16 + q * 4 + r;
                if (m < 36) {
                    #pragma unroll
                    for (int y = 0; y < 2; ++y)
                        Fl[m][w * 32 + y * 16 + lm] = f2bf(acc[x][y][r]);
                }
            }
        __syncthreads();                // Fl visible; frg complete

        // issue next n0's first WT chunk: hides under conv phase
        if (n0 < 384)
            STAGE_B(0, n0 + 128, 0);

        // conv + tanh + avgpool; thread: 4 out rows x 4 d
        float4 f[8], a[8];
        #pragma unroll
        for (int k = 0; k < 8; ++k) {
            f[k] = bf4f(frg[k]);
            a[k] = bf4f(*(const ushort4*)&Fl[g * 4 + k][dl]);
        }
        float4 ty[6];
        #pragma unroll
        for (int k = 0; k < 6; ++k) {
            float4 y;
            y.x = bias + w00*f[k].x + w01*f[k+1].x + w02*f[k+2].x + w10*a[k].x + w11*a[k+1].x + w12*a[k+2].x;
            y.y = bias + w00*f[k].y + w01*f[k+1].y + w02*f[k+2].y + w10*a[k].y + w11*a[k+1].y + w12*a[k+2].y;
            y.z = bias + w00*f[k].z + w01*f[k+1].z + w02*f[k+2].z + w10*a[k].z + w11*a[k+1].z + w12*a[k+2].z;
            y.w = bias + w00*f[k].w + w01*f[k+1].w + w02*f[k+2].w + w10*a[k].w + w11*a[k+1].w + w12*a[k+2].w;
            y.x = ftanh(y.x); y.y = ftanh(y.y); y.z = ftanh(y.z); y.w = ftanh(y.w);
            ty[k] = y;
        }
        #pragma unroll
        for (int r = 0; r < 4; ++r) {
            float4 res;
            res.x = (ty[r].x + ty[r+1].x + ty[r+2].x) * third;
            res.y = (ty[r].y + ty[r+1].y + ty[r+2].y) * third;
            res.z = (ty[r].z + ty[r+1].z + ty[r+2].z) * third;
            res.w = (ty[r].w + ty[r+1].w + ty[r+2].w) * third;
            *(float4*)(o + (size_t)(s0 + g * 4 + r) * 512 + n0 + dl) = res;
        }
        // next n0's kb_i=0 barrier separates conv reads of Fl from region rewrite
    }
#undef STAGE_B
}

// ---------- launcher ----------
extern "C" void kernel_launch(void* const* d_in, const int* in_sizes, int n_in,
                              void* d_out, int out_size, void* d_ws, size_t ws_size,
                              hipStream_t stream)
{
    const float* F0r = (const float*)d_in[0];
    const float* F1r = (const float*)d_in[1];
    const float* m0  = (const float*)d_in[2];
    const float* m1  = (const float*)d_in[3];
    const float* W0  = (const float*)d_in[4];
    const float* W1  = (const float*)d_in[5];
    const float* cw  = (const float*)d_in[6];
    const float* cb  = (const float*)d_in[7];
    float* out = (float*)d_out;

    char* ws = (char*)d_ws;
    u16* F0b   = (u16*)(ws);                      // 16 MiB  [B,S,D] bf16
    u16* F1b   = (u16*)(ws + 16777216);           // 16 MiB
    float* sq0 = (float*)(ws + 50331648);         // 64 KiB
    float* sq1 = (float*)(ws + 50397184);         // 64 KiB
    u16* WT0   = (u16*)(ws + 50462720);           // 256 KiB [D,S] bf16
    u16* WT1   = (u16*)(ws + 50724864);           // 256 KiB

    // main 16384 blocks + 128 transpose-tile tail blocks
    prep_kernel<<<16512, 128, 0, stream>>>(F0r, F1r, m0, m1, W0, W1,
                                           F0b, F1b, WT0, WT1, sq0, sq1);
    fused_kernel<<<dim3(8, 64, 2), 256, 0, stream>>>(F0b, F1b, sq0, sq1,
                                                     WT0, WT1, F0b, F1b,
                                                     cw, cb, out);
}

// Round 7
// 188.873 us; speedup vs baseline: 1.1019x; 1.1019x over previous
//
#include <hip/hip_runtime.h>

typedef unsigned short u16;
typedef __attribute__((ext_vector_type(8))) short short8;
typedef __attribute__((ext_vector_type(4))) float f32x4;

// ---------- helpers ----------
__device__ inline u16 f2bf(float f) {
    union { float f; unsigned u; } v; v.f = f;
    unsigned u = v.u;
    unsigned r = (u + 0x7FFFu + ((u >> 16) & 1u)) >> 16;
    return (u16)r;
}
__device__ inline float bf2f(u16 h) {
    union { unsigned u; float f; } v; v.u = ((unsigned)h) << 16;
    return v.f;
}
// fast rcp/sqrt (~2^-21 rel err; tolerance is bf16-level 0.0078 -> free).
__device__ inline float frcp(float x) { return __builtin_amdgcn_rcpf(x); }
__device__ inline float fsqrt(float x) { return __builtin_amdgcn_sqrtf(x); }
__device__ inline float ftanh(float x) {
    float e = __expf(2.f * x);
    return 1.f - 2.f * frcp(e + 1.f);
}
__device__ inline float4 bf4f(ushort4 u) {
    float4 f; f.x = bf2f(u.x); f.y = bf2f(u.y); f.z = bf2f(u.z); f.w = bf2f(u.w);
    return f;
}

// 16B async global->LDS. Pass a WAVE-UNIFORM LDS base; HW adds lane*16.
// Global src addr is per-lane. Zero VGPR staging cost.
typedef const __attribute__((address_space(1))) void* gas_ptr;
typedef __attribute__((address_space(3))) void* las_ptr;
__device__ __forceinline__ void gl2lds16(const u16* g, u16* l) {
    __builtin_amdgcn_global_load_lds((gas_ptr)(const void*)g, (las_ptr)(void*)l, 16, 0, 0);
}

// ---------- kernel 1: mask + bf16 cast + row norms (wave-per-row) + W transpose tail ----------
// Rounds 0-6 back-solve: the old 16384x128-thread version cost ~95-105 us
// (roofline 16 us) -- per-block fixed costs (LDS round-trip + 2 barriers per
// single row) dominated. New structure: 1024 main blocks x 4 waves; each WAVE
// owns rows (no barrier, no LDS): lane holds 8 floats of the row, reduction is
// pure shfl_xor, stores are 16B/lane.
__global__ __launch_bounds__(256) void prep_kernel(
    const float* __restrict__ F0r, const float* __restrict__ F1r,
    const float* __restrict__ m0, const float* __restrict__ m1,
    const float* __restrict__ W0, const float* __restrict__ W1,
    u16* __restrict__ F0b, u16* __restrict__ F1b,
    u16* __restrict__ WT0, u16* __restrict__ WT1,
    float* __restrict__ sq0, float* __restrict__ sq1)
{
    int bx = blockIdx.x;
    int t = threadIdx.x;
    if (bx >= 1024) {
        // W [256 s][512 d] fp32 -> WT [512 d][256 s] bf16 via [32 s][64 d] tiles.
        __shared__ u16 Wl[64][40];
        int idx2 = bx - 1024;               // 0..127
        int a = idx2 >> 6;
        int tile = idx2 & 63;
        int s0t = (tile >> 3) * 32, d0 = (tile & 7) * 64;
        const float* W = a ? W1 : W0;
        u16* WT = a ? WT1 : WT0;
        #pragma unroll
        for (int i = 0; i < 2; ++i) {
            int idx = i * 1024 + t * 4;     // 0..2044, step 4
            int sl = idx >> 6, dl = idx & 63;
            float4 v = *(const float4*)(W + (size_t)(s0t + sl) * 512 + d0 + dl);
            Wl[dl + 0][sl] = f2bf(v.x);
            Wl[dl + 1][sl] = f2bf(v.y);
            Wl[dl + 2][sl] = f2bf(v.z);
            Wl[dl + 3][sl] = f2bf(v.w);
        }
        __syncthreads();
        #pragma unroll
        for (int i = 0; i < 2; ++i) {
            int idx = i * 1024 + t * 4;
            int dl = idx >> 5, sl = idx & 31;
            ushort4 v;
            v.x = Wl[dl][sl + 0]; v.y = Wl[dl][sl + 1];
            v.z = Wl[dl][sl + 2]; v.w = Wl[dl][sl + 3];
            *(ushort4*)(WT + (size_t)(d0 + dl) * 256 + s0t + sl) = v;
        }
        return;
    }
    // main: wave-per-row, grid-stride. 4096 waves, 16384 rows -> 4 rows/wave.
    int gw = (bx << 2) + (t >> 6);          // global wave id 0..4095
    int lane = t & 63;
    for (int row = gw; row < 16384; row += 4096) {
        size_t base = (size_t)row * 512 + lane * 8;   // 8 floats per lane
        float mk0 = m0[row], mk1 = m1[row];
        float4 a0 = *(const float4*)(F0r + base);
        float4 a1 = *(const float4*)(F0r + base + 4);
        float4 b0 = *(const float4*)(F1r + base);
        float4 b1 = *(const float4*)(F1r + base + 4);
        a0.x *= mk0; a0.y *= mk0; a0.z *= mk0; a0.w *= mk0;
        a1.x *= mk0; a1.y *= mk0; a1.z *= mk0; a1.w *= mk0;
        b0.x *= mk1; b0.y *= mk1; b0.z *= mk1; b0.w *= mk1;
        b1.x *= mk1; b1.y *= mk1; b1.z *= mk1; b1.w *= mk1;
        ushort4 u0a, u0b, u1a, u1b;
        u0a.x = f2bf(a0.x); u0a.y = f2bf(a0.y); u0a.z = f2bf(a0.z); u0a.w = f2bf(a0.w);
        u0b.x = f2bf(a1.x); u0b.y = f2bf(a1.y); u0b.z = f2bf(a1.z); u0b.w = f2bf(a1.w);
        u1a.x = f2bf(b0.x); u1a.y = f2bf(b0.y); u1a.z = f2bf(b0.z); u1a.w = f2bf(b0.w);
        u1b.x = f2bf(b1.x); u1b.y = f2bf(b1.y); u1b.z = f2bf(b1.z); u1b.w = f2bf(b1.w);
        *(ushort4*)(F0b + base)     = u0a;
        *(ushort4*)(F0b + base + 4) = u0b;
        *(ushort4*)(F1b + base)     = u1a;
        *(ushort4*)(F1b + base + 4) = u1b;
        float s0p = a0.x*a0.x + a0.y*a0.y + a0.z*a0.z + a0.w*a0.w
                  + a1.x*a1.x + a1.y*a1.y + a1.z*a1.z + a1.w*a1.w;
        float s1p = b0.x*b0.x + b0.y*b0.y + b0.z*b0.z + b0.w*b0.w
                  + b1.x*b1.x + b1.y*b1.y + b1.z*b1.z + b1.w*b1.w;
        #pragma unroll
        for (int off = 32; off > 0; off >>= 1) {
            s0p += __shfl_xor(s0p, off);
            s1p += __shfl_xor(s1p, off);
        }
        if (lane == 0) { sq0[row] = s0p; sq1[row] = s1p; }
    }
}

// ---------- kernel 2: FUSED cross-GEMM strip + Fa-GEMM + conv + tanh + avgpool ----------
// Round-6 structure + XCD-grouping job swizzle. Round 6 measured FETCH=175 MB:
// the 8 s0-blocks sharing one G-panel (256 KB) were consecutive in linear
// block id -> round-robin dispatch spread them over 8 XCDs -> 8x HBM fetch of
// G. Remap so the 8 s0-blocks of one (b,side) occupy ids == same value mod 8
// (same XCD, within 64 dispatches) -> G is fetched once per XCD-L2.
__global__ __launch_bounds__(256) void fused_kernel(
    const u16* __restrict__ F0b, const u16* __restrict__ F1b,
    const float* __restrict__ sq0, const float* __restrict__ sq1,
    const u16* __restrict__ WT0, const u16* __restrict__ WT1,
    const float* __restrict__ cw, const float* __restrict__ cb,
    float* __restrict__ out)
{
    __shared__ __align__(16) u16 Al[36][264];     // A-strip, phase-2 A operand, 19.0 KB
    __shared__ __align__(16) u16 region[21136];   // 42.3 KB union (ph1: G|S, ph2: BlBuf|Fl)
    u16 (*Fl)[132] = (u16(*)[132])(region + 16384);

    // XCD-grouping decode: L = qq*64 + s0i*8 + x;  code = qq*8 + x = 2b+side.
    // For fixed (b,side), the 8 s0i blocks sit at L == code&7 (mod 8) -> same XCD.
    int L = blockIdx.x + (blockIdx.y << 3) + (blockIdx.z << 9);
    int qq = L >> 6, rr = L & 63;
    int s0i = rr >> 3;
    int code = qq * 8 + (rr & 7);   // 0..127
    int b = code >> 1, side = code & 1;
    int s0 = s0i * 32;

    const u16* Sp  = (side ? F0b : F1b) + (size_t)b * 131072;  // strip operand
    const u16* Gp  = (side ? F1b : F0b) + (size_t)b * 131072;  // full-K operand
    const float* sqS = (side ? sq0 : sq1) + b * 256;
    const float* sqG = (side ? sq1 : sq0) + b * 256;
    const u16* WT = side ? WT1 : WT0;
    const u16* Fb = (side ? F1b : F0b) + (size_t)b * 131072;   // conv F source
    float* o = out + (size_t)side * 8388608 + (size_t)b * 131072;

    const int t = threadIdx.x;
    const int lane = t & 63, w = t >> 6;
    const int q = lane >> 4, lm = lane & 15;

    // ===== phase 1: P[m][j] = S[m,:].G[j,:] for m=0..47 (36 used), j=0..255 =====
    f32x4 acc1[3][4];
    #pragma unroll
    for (int x = 0; x < 3; ++x)
        #pragma unroll
        for (int cn = 0; cn < 4; ++cn)
            acc1[x][cn] = (f32x4){0.f, 0.f, 0.f, 0.f};

    for (int kc = 0; kc < 512; kc += 64) {
        __syncthreads();                 // prior chunk's MFMA reads done
        // stage G chunk: 256 rows x 64 k, inverse-swizzled source
        #pragma unroll
        for (int i = 0; i < 8; ++i) {
            int idx = i * 256 + t;
            int r = idx >> 3, seg = idx & 7;
            int ss = seg ^ (r & 7);
            gl2lds16(Gp + (size_t)r * 512 + kc + ss * 8,
                     &region[(i * 256 + w * 64) * 8]);
        }
        // stage S chunk: 48 rows x 64 k (rows clamped; OOB zeroed in epilogue)
        {
            int idx = t;
            int r = idx >> 3, seg = idx & 7;
            int ss = seg ^ (r & 7);
            int s = s0 - 2 + r; s = s < 0 ? 0 : (s > 255 ? 255 : s);
            gl2lds16(Sp + (size_t)s * 512 + kc + ss * 8,
                     &region[16384 + (w * 64) * 8]);
        }
        if (t < 128) {
            int idx = 256 + t;
            int r = idx >> 3, seg = idx & 7;
            int ss = seg ^ (r & 7);
            int s = s0 - 2 + r; s = s < 0 ? 0 : (s > 255 ? 255 : s);
            gl2lds16(Sp + (size_t)s * 512 + kc + ss * 8,
                     &region[16384 + (256 + w * 64) * 8]);
        }
        __syncthreads();                 // chunk staged
        #pragma unroll
        for (int ks = 0; ks < 64; ks += 32) {
            int su = (((ks >> 3) + q) ^ (lm & 7)) * 8;   // read-side swizzle
            short8 af[3], bfr[4];
            #pragma unroll
            for (int x = 0; x < 3; ++x)
                af[x] = *(const short8*)&region[16384 + (x * 16 + lm) * 64 + su];
            #pragma unroll
            for (int cn = 0; cn < 4; ++cn)
                bfr[cn] = *(const short8*)&region[(w * 64 + cn * 16 + lm) * 64 + su];
            #pragma unroll
            for (int x = 0; x < 3; ++x)
                #pragma unroll
                for (int cn = 0; cn < 4; ++cn)
                    acc1[x][cn] = __builtin_amdgcn_mfma_f32_16x16x32_bf16(
                        af[x], bfr[cn], acc1[x][cn], 0, 0, 0);
        }
    }
    __syncthreads();                     // all phase-1 region reads done

    // epilogue: d2 -> A, write strip into Al (C-layout: row=x*16+q*4+r, col=w*64+cn*16+lm)
    float sqg[4];
    #pragma unroll
    for (int cn = 0; cn < 4; ++cn) sqg[cn] = sqG[w * 64 + cn * 16 + lm];
    #pragma unroll
    for (int x = 0; x < 3; ++x) {
        #pragma unroll
        for (int r = 0; r < 4; ++r) {
            int m = x * 16 + q * 4 + r;
            if (m < 36) {
                int s = s0 - 2 + m;
                bool ok = (unsigned)s < 256u;
                float sqs = ok ? sqS[s] : 0.f;
                #pragma unroll
                for (int cn = 0; cn < 4; ++cn) {
                    float d2 = fmaxf(sqs + sqg[cn] - 2.f * acc1[x][cn][r], 0.f);
                    float a = ok ? frcp(1.f + fsqrt(d2)) : 0.f;
                    Al[m][w * 64 + cn * 16 + lm] = f2bf(a);
                }
            }
        }
    }
    // no barrier needed before STAGE_B: epilogue doesn't touch region; the
    // n0-loop's kb_i=0 barrier makes Al visible + drains the stage.

    // ===== phase 2: Fa-GEMM + conv (round-5 fa_conv, Al computed in-kernel) =====
#define STAGE_B(bufo, nn, kb) do {                                             \
    _Pragma("unroll")                                                          \
    for (int i_ = 0; i_ < 4; ++i_) {                                           \
        int idx_ = i_ * 256 + t;                                               \
        int r_ = idx_ >> 3, seg_ = idx_ & 7;                                   \
        int ss_ = seg_ ^ (r_ & 7);                                             \
        gl2lds16(WT + (size_t)((nn) + r_) * 256 + (kb) + ss_ * 8,              \
                 &region[(bufo) + (i_ * 256 + w * 64) * 8]);                   \
    } } while (0)

    // A-fragment row pointers; x=2 rows >=36 dead (outputs discarded) -> clamp
    const u16* aRow[3];
    aRow[0] = &Al[lm][0];
    aRow[1] = &Al[16 + lm][0];
    aRow[2] = &Al[(lm < 4) ? (32 + lm) : 0][0];

    float w00 = cw[0], w01 = cw[1], w02 = cw[2];
    float w10 = cw[3], w11 = cw[4], w12 = cw[5];
    float bias = cb[0];
    const float third = 1.f / 3.f;
    const int g = t >> 5;               // 0..7: out-row group (4 rows)
    const int dl = (t & 31) * 4;        // d within chunk

    STAGE_B(0, 0, 0);                   // prologue: n0=0, kb=0 -> buf0

    for (int n0 = 0; n0 < 512; n0 += 128) {
        f32x4 acc[3][2];
        #pragma unroll
        for (int x = 0; x < 3; ++x)
            #pragma unroll
            for (int y = 0; y < 2; ++y)
                acc[x][y] = (f32x4){0.f, 0.f, 0.f, 0.f};

        #pragma unroll
        for (int kb_i = 0; kb_i < 4; ++kb_i) {
            __syncthreads();            // drains stage kb_i (hidden under prior phase)
            if (kb_i < 3)
                STAGE_B(((kb_i + 1) & 1) * 8192, n0, (kb_i + 1) * 64);
            const int cbuf = (kb_i & 1) * 8192;
            const int kb = kb_i * 64;
            #pragma unroll
            for (int ks = 0; ks < 64; ks += 32) {
                short8 af[3], bfr[2];
                #pragma unroll
                for (int x = 0; x < 3; ++x)
                    af[x] = *(const short8*)(aRow[x] + kb + ks + q * 8);
                #pragma unroll
                for (int y = 0; y < 2; ++y) {
                    int rb = w * 32 + y * 16 + lm;
                    int su = (((ks >> 3) + q) ^ (lm & 7)) * 8;
                    bfr[y] = *(const short8*)&region[cbuf + rb * 64 + su];
                }
                #pragma unroll
                for (int x = 0; x < 3; ++x)
                    #pragma unroll
                    for (int y = 0; y < 2; ++y)
                        acc[x][y] = __builtin_amdgcn_mfma_f32_16x16x32_bf16(
                            af[x], bfr[y], acc[x][y], 0, 0, 0);
            }
        }

        // issue conv F-loads: latency overlaps Fl-write phase, drained at barrier
        ushort4 frg[8];
        #pragma unroll
        for (int k = 0; k < 8; ++k) {
            int s = s0 + g * 4 - 2 + k;
            ushort4 z = {0, 0, 0, 0};
            frg[k] = ((unsigned)s < 256u)
                   ? *(const ushort4*)(Fb + (size_t)s * 512 + n0 + dl) : z;
        }

        // stage Fa (bf16) into Fl
        #pragma unroll
        for (int x = 0; x < 3; ++x)
            #pragma unroll
            for (int r = 0; r < 4; ++r) {
                int m = x * 16 + q * 4 + r;
                if (m < 36) {
                    #pragma unroll
                    for (int y = 0; y < 2; ++y)
                        Fl[m][w * 32 + y * 16 + lm] = f2bf(acc[x][y][r]);
                }
            }
        __syncthreads();                // Fl visible; frg complete

        // issue next n0's first WT chunk: hides under conv phase
        if (n0 < 384)
            STAGE_B(0, n0 + 128, 0);

        // conv + tanh + avgpool; thread: 4 out rows x 4 d
        float4 f[8], a[8];
        #pragma unroll
        for (int k = 0; k < 8; ++k) {
            f[k] = bf4f(frg[k]);
            a[k] = bf4f(*(const ushort4*)&Fl[g * 4 + k][dl]);
        }
        float4 ty[6];
        #pragma unroll
        for (int k = 0; k < 6; ++k) {
            float4 y;
            y.x = bias + w00*f[k].x + w01*f[k+1].x + w02*f[k+2].x + w10*a[k].x + w11*a[k+1].x + w12*a[k+2].x;
            y.y = bias + w00*f[k].y + w01*f[k+1].y + w02*f[k+2].y + w10*a[k].y + w11*a[k+1].y + w12*a[k+2].y;
            y.z = bias + w00*f[k].z + w01*f[k+1].z + w02*f[k+2].z + w10*a[k].z + w11*a[k+1].z + w12*a[k+2].z;
            y.w = bias + w00*f[k].w + w01*f[k+1].w + w02*f[k+2].w + w10*a[k].w + w11*a[k+1].w + w12*a[k+2].w;
            y.x = ftanh(y.x); y.y = ftanh(y.y); y.z = ftanh(y.z); y.w = ftanh(y.w);
            ty[k] = y;
        }
        #pragma unroll
        for (int r = 0; r < 4; ++r) {
            float4 res;
            res.x = (ty[r].x + ty[r+1].x + ty[r+2].x) * third;
            res.y = (ty[r].y + ty[r+1].y + ty[r+2].y) * third;
            res.z = (ty[r].z + ty[r+1].z + ty[r+2].z) * third;
            res.w = (ty[r].w + ty[r+1].w + ty[r+2].w) * third;
            *(float4*)(o + (size_t)(s0 + g * 4 + r) * 512 + n0 + dl) = res;
        }
        // next n0's kb_i=0 barrier separates conv reads of Fl from region rewrite
    }
#undef STAGE_B
}

// ---------- launcher ----------
extern "C" void kernel_launch(void* const* d_in, const int* in_sizes, int n_in,
                              void* d_out, int out_size, void* d_ws, size_t ws_size,
                              hipStream_t stream)
{
    const float* F0r = (const float*)d_in[0];
    const float* F1r = (const float*)d_in[1];
    const float* m0  = (const float*)d_in[2];
    const float* m1  = (const float*)d_in[3];
    const float* W0  = (const float*)d_in[4];
    const float* W1  = (const float*)d_in[5];
    const float* cw  = (const float*)d_in[6];
    const float* cb  = (const float*)d_in[7];
    float* out = (float*)d_out;

    char* ws = (char*)d_ws;
    u16* F0b   = (u16*)(ws);                      // 16 MiB  [B,S,D] bf16
    u16* F1b   = (u16*)(ws + 16777216);           // 16 MiB
    float* sq0 = (float*)(ws + 50331648);         // 64 KiB
    float* sq1 = (float*)(ws + 50397184);         // 64 KiB
    u16* WT0   = (u16*)(ws + 50462720);           // 256 KiB [D,S] bf16
    u16* WT1   = (u16*)(ws + 50724864);           // 256 KiB

    // 1024 main (wave-per-row) + 128 transpose-tile tail blocks
    prep_kernel<<<1152, 256, 0, stream>>>(F0r, F1r, m0, m1, W0, W1,
                                          F0b, F1b, WT0, WT1, sq0, sq1);
    fused_kernel<<<dim3(8, 64, 2), 256, 0, stream>>>(F0b, F1b, sq0, sq1,
                                                     WT0, WT1, cw, cb, out);
}